// Round 1
// baseline (419.047 us; speedup 1.0000x reference)
//
#include <hip/hip_runtime.h>
#include <math.h>

// Problem constants (match reference)
#define N_NEU   8192
#define IN_SZ   512
#define OUT_SZ  512
constexpr float TAU_INV = 0.1f;   // 1/10.0
constexpr float G_GAIN  = 1.5f;

// ---------------------------------------------------------------------------
// init: rates = tanh(potentials); zero the split-K accumulators and d_out[0:512]
// ---------------------------------------------------------------------------
__global__ void init_kernel(const float* __restrict__ pot,
                            float* __restrict__ rates,
                            float* __restrict__ drive,
                            float* __restrict__ y,
                            float* __restrict__ out_head) {
    int j = blockIdx.x * blockDim.x + threadIdx.x;
    if (j < N_NEU) {
        float p = pot[j];
        rates[j] = tanhf(p);
        drive[j] = 0.0f;
        y[j]     = 0.0f;
    }
    if (j < OUT_SZ) out_head[j] = 0.0f;
}

// ---------------------------------------------------------------------------
// Split-K GEMV accumulate: y[j] += sum_{i in k-tile} x[i] * M[i][j]
// Column-major over threads: thread owns 4 consecutive columns (float4 load).
// x-tile staged in LDS (uniform broadcast read). Partial sums atomicAdd'ed.
//   grid.x = n4 / blockDim.x   (n4 = N/4 column-quads)
//   grid.y = K / KPB           (k-tiles)
// ---------------------------------------------------------------------------
template<int KPB>
__global__ void gemv_acc(const float* __restrict__ x,
                         const float* __restrict__ M,
                         float* __restrict__ y,
                         int n4) {
    __shared__ float xs[KPB];
    const int k0 = blockIdx.y * KPB;
    for (int t = threadIdx.x; t < KPB; t += blockDim.x) xs[t] = x[k0 + t];
    __syncthreads();

    const int col4 = blockIdx.x * blockDim.x + threadIdx.x;
    const float4* Mp = (const float4*)M + (size_t)k0 * n4 + col4;

    float4 acc = make_float4(0.f, 0.f, 0.f, 0.f);
#pragma unroll 8
    for (int i = 0; i < KPB; ++i) {
        float  s = xs[i];
        float4 m = Mp[(size_t)i * n4];
        acc.x = fmaf(s, m.x, acc.x);
        acc.y = fmaf(s, m.y, acc.y);
        acc.z = fmaf(s, m.z, acc.z);
        acc.w = fmaf(s, m.w, acc.w);
    }

    float* yp = y + (size_t)col4 * 4;
    atomicAdd(yp + 0, acc.x);
    atomicAdd(yp + 1, acc.y);
    atomicAdd(yp + 2, acc.z);
    atomicAdd(yp + 3, acc.w);
}

// ---------------------------------------------------------------------------
// finalize: pot_new = pot + (-pot + G*y + drive)/TAU ; gen = tanh(pot_new)
// writes pot_new into d_out[512:8704]
// ---------------------------------------------------------------------------
__global__ void finalize_kernel(const float* __restrict__ pot,
                                const float* __restrict__ y,
                                const float* __restrict__ drive,
                                float* __restrict__ pot_out,
                                float* __restrict__ gen) {
    int j = blockIdx.x * blockDim.x + threadIdx.x;
    float p  = pot[j];
    float pn = p + (-p + G_GAIN * y[j] + drive[j]) * TAU_INV;
    pot_out[j] = pn;
    gen[j]     = tanhf(pn);
}

// ---------------------------------------------------------------------------
extern "C" void kernel_launch(void* const* d_in, const int* in_sizes, int n_in,
                              void* d_out, int out_size, void* d_ws, size_t ws_size,
                              hipStream_t stream) {
    const float* inputs   = (const float*)d_in[0];   // [512]
    const float* pot      = (const float*)d_in[1];   // [8192]
    const float* W_in     = (const float*)d_in[2];   // [512, 8192]
    const float* synapses = (const float*)d_in[3];   // [8192, 8192]
    const float* W_out    = (const float*)d_in[4];   // [8192, 512]

    float* out = (float*)d_out;          // [0:512] output, [512:8704] pot_new

    float* ws_rates = (float*)d_ws;                  // 8192
    float* ws_drive = ws_rates + N_NEU;              // 8192
    float* ws_y     = ws_drive + N_NEU;              // 8192
    float* ws_gen   = ws_y     + N_NEU;              // 8192

    // 1) init: rates, zero accumulators + output head
    init_kernel<<<dim3(N_NEU / 256), dim3(256), 0, stream>>>(
        pot, ws_rates, ws_drive, ws_y, out);

    // 2) drive = inputs @ W_in   (K=512, N=8192) : 16 MB
    //    grid: 8 col-tiles x 32 k-tiles (KPB=16) = 256 blocks
    gemv_acc<16><<<dim3(N_NEU / 4 / 256, IN_SZ / 16), dim3(256), 0, stream>>>(
        inputs, W_in, ws_drive, N_NEU / 4);

    // 3) y = rates @ synapses   (K=8192, N=8192) : 256 MB  <-- the big one
    //    grid: 8 col-tiles x 64 k-tiles (KPB=128) = 512 blocks, 2/CU
    gemv_acc<128><<<dim3(N_NEU / 4 / 256, N_NEU / 128), dim3(256), 0, stream>>>(
        ws_rates, synapses, ws_y, N_NEU / 4);

    // 4) pot_new + gen_net
    finalize_kernel<<<dim3(N_NEU / 256), dim3(256), 0, stream>>>(
        pot, ws_y, ws_drive, out + OUT_SZ, ws_gen);

    // 5) output = gen @ W_out   (K=8192, N=512) : 16 MB
    //    grid: 1 col-tile (128 threads) x 256 k-tiles (KPB=32)
    gemv_acc<32><<<dim3(1, N_NEU / 32), dim3(128), 0, stream>>>(
        ws_gen, W_out, out, OUT_SZ / 4);
}

// Round 2
// 407.592 us; speedup vs baseline: 1.0281x; 1.0281x over previous
//
#include <hip/hip_runtime.h>
#include <math.h>

// Problem constants (match reference)
#define N_NEU   8192
#define IN_SZ   512
#define OUT_SZ  512
#define N4      (N_NEU / 4)      // 2048 float4 column-quads per row (W_in & synapses)
#define KPB     64               // k-rows per block (accumulate kernel)
constexpr float TAU_INV = 0.1f;
constexpr float G_GAIN  = 1.5f;

// ---------------------------------------------------------------------------
// K1: acc[j] += sum_k xs[k] * M[k][j]  for M in {synapses (xs=G*tanh(pot)),
//                                               W_in     (xs=inputs)}
// grid = (8 col-tiles, 128 syn k-tiles + 8 W_in k-tiles), block = 256
// Thread owns 4 consecutive columns (float4). xs staged in LDS (broadcast).
// ---------------------------------------------------------------------------
__global__ __launch_bounds__(256)
void accum_kernel(const float* __restrict__ pot,
                  const float* __restrict__ inputs,
                  const float* __restrict__ synapses,
                  const float* __restrict__ W_in,
                  float* __restrict__ acc_buf) {
    __shared__ float xs[KPB];
    const int by = blockIdx.y;
    const float4* M;
    int k0;
    if (by < N_NEU / KPB) {                       // synapses tile
        k0 = by * KPB;
        M  = (const float4*)synapses;
        if (threadIdx.x < KPB)
            xs[threadIdx.x] = G_GAIN * tanhf(pot[k0 + threadIdx.x]);
    } else {                                      // W_in tile
        k0 = (by - N_NEU / KPB) * KPB;
        M  = (const float4*)W_in;
        if (threadIdx.x < KPB)
            xs[threadIdx.x] = inputs[k0 + threadIdx.x];
    }
    __syncthreads();

    const int col4 = blockIdx.x * blockDim.x + threadIdx.x;
    const float4* Mp = M + (size_t)k0 * N4 + col4;

    float4 acc = make_float4(0.f, 0.f, 0.f, 0.f);
#pragma unroll 8
    for (int i = 0; i < KPB; ++i) {
        float  s = xs[i];
        float4 m = Mp[(size_t)i * N4];
        acc.x = fmaf(s, m.x, acc.x);
        acc.y = fmaf(s, m.y, acc.y);
        acc.z = fmaf(s, m.z, acc.z);
        acc.w = fmaf(s, m.w, acc.w);
    }

    float* yp = acc_buf + (size_t)col4 * 4;
    atomicAdd(yp + 0, acc.x);
    atomicAdd(yp + 1, acc.y);
    atomicAdd(yp + 2, acc.z);
    atomicAdd(yp + 3, acc.w);
}

// ---------------------------------------------------------------------------
// K2: blocks [0,128): out-GEMV k-tiles — recompute pot_new/gen for own 64 rows,
//                     accumulate into out[0:512] (atomics, out pre-zeroed).
//     blocks [128,192): elementwise pot_new -> d_out[512:8704].
// block = 128 threads.
// ---------------------------------------------------------------------------
#define K2_KPB   64
#define OUT4     (OUT_SZ / 4)    // 128 float4 col-quads in W_out rows
__global__ __launch_bounds__(128)
void finish_kernel(const float* __restrict__ pot,
                   const float* __restrict__ acc_buf,
                   const float* __restrict__ W_out,
                   float* __restrict__ out) {
    const int b = blockIdx.x;
    if (b < N_NEU / K2_KPB) {
        // ---- out = tanh(pot_new) @ W_out, split-K tile ----
        __shared__ float xs[K2_KPB];
        const int k0 = b * K2_KPB;
        if (threadIdx.x < K2_KPB) {
            int k = k0 + threadIdx.x;
            float p  = pot[k];
            float pn = p + (acc_buf[k] - p) * TAU_INV;
            xs[threadIdx.x] = tanhf(pn);
        }
        __syncthreads();

        const int col4 = threadIdx.x;             // 128 quads = 512 cols
        const float4* Wp = (const float4*)W_out + (size_t)k0 * OUT4 + col4;
        float4 acc = make_float4(0.f, 0.f, 0.f, 0.f);
#pragma unroll 8
        for (int i = 0; i < K2_KPB; ++i) {
            float  s = xs[i];
            float4 m = Wp[(size_t)i * OUT4];
            acc.x = fmaf(s, m.x, acc.x);
            acc.y = fmaf(s, m.y, acc.y);
            acc.z = fmaf(s, m.z, acc.z);
            acc.w = fmaf(s, m.w, acc.w);
        }
        float* op = out + (size_t)col4 * 4;
        atomicAdd(op + 0, acc.x);
        atomicAdd(op + 1, acc.y);
        atomicAdd(op + 2, acc.z);
        atomicAdd(op + 3, acc.w);
    } else {
        // ---- pot_new elementwise -> d_out[512:] ----
        int j = (b - N_NEU / K2_KPB) * 128 + threadIdx.x;
        float p  = pot[j];
        float pn = p + (acc_buf[j] - p) * TAU_INV;
        out[OUT_SZ + j] = pn;
    }
}

// ---------------------------------------------------------------------------
extern "C" void kernel_launch(void* const* d_in, const int* in_sizes, int n_in,
                              void* d_out, int out_size, void* d_ws, size_t ws_size,
                              hipStream_t stream) {
    const float* inputs   = (const float*)d_in[0];   // [512]
    const float* pot      = (const float*)d_in[1];   // [8192]
    const float* W_in     = (const float*)d_in[2];   // [512, 8192]
    const float* synapses = (const float*)d_in[3];   // [8192, 8192]
    const float* W_out    = (const float*)d_in[4];   // [8192, 512]

    float* out     = (float*)d_out;                  // [0:512] out, [512:8704] pot_new
    float* acc_buf = (float*)d_ws;                   // 8192 floats: drive + G*(rates@syn)

    // zero the two atomic accumulators (tiny memset nodes, capturable)
    hipMemsetAsync(acc_buf, 0, N_NEU * sizeof(float), stream);
    hipMemsetAsync(out, 0, OUT_SZ * sizeof(float), stream);

    // K1: 8 col-tiles x (128 synapse + 8 W_in) k-tiles = 1088 blocks
    accum_kernel<<<dim3(N4 / 256, N_NEU / KPB + IN_SZ / KPB), dim3(256), 0, stream>>>(
        pot, inputs, synapses, W_in, acc_buf);

    // K2: 128 out-gemv tiles + 64 elementwise blocks
    finish_kernel<<<dim3(N_NEU / K2_KPB + N_NEU / 128), dim3(128), 0, stream>>>(
        pot, acc_buf, W_out, out);
}

// Round 3
// 405.311 us; speedup vs baseline: 1.0339x; 1.0056x over previous
//
#include <hip/hip_runtime.h>
#include <math.h>

// Problem constants (match reference)
#define N_NEU   8192
#define IN_SZ   512
#define OUT_SZ  512
#define N4      (N_NEU / 4)          // 2048 float4 col-quads per row of W_in/synapses
#define OUT4    (OUT_SZ / 4)         // 128 quads per W_out row
#define KPB     64                   // k-rows per K1 block
#define SYN_TILES (N_NEU / KPB)      // 128
#define WIN_TILES (IN_SZ / KPB)      // 8
#define TILES     (SYN_TILES + WIN_TILES)  // 136
#define K2_KPB  128                  // k-rows per K2 out-gemv tile
#define OTILES  (N_NEU / K2_KPB)     // 64
constexpr float TAU_INV = 0.1f;
constexpr float G_GAIN  = 1.5f;

// ---------------------------------------------------------------------------
// K1: partial[by*8+bx][0:1024] = sum_{k in tile by} xs[k] * M[k][cols of bx]
//     xs = G*tanh(pot) for synapses tiles, inputs for W_in tiles.
//     NO atomics: each block owns a private 1024-float partial (full overwrite).
//     Last tile row also zeroes out[0:512] for K2's atomics.
// grid = (8, 136), block = 256
// ---------------------------------------------------------------------------
__global__ __launch_bounds__(256)
void accum_kernel(const float* __restrict__ pot,
                  const float* __restrict__ inputs,
                  const float* __restrict__ synapses,
                  const float* __restrict__ W_in,
                  float4* __restrict__ P4,          // [136*8][256] float4
                  float* __restrict__ out) {
    __shared__ float xs[KPB];
    const int bx = blockIdx.x, by = blockIdx.y;
    const int tid = threadIdx.x;
    const float4* M;
    int k0;
    if (by < SYN_TILES) {                     // synapses tile
        k0 = by * KPB;
        M  = (const float4*)synapses;
        if (tid < KPB) xs[tid] = G_GAIN * tanhf(pot[k0 + tid]);
    } else {                                  // W_in tile
        k0 = (by - SYN_TILES) * KPB;
        M  = (const float4*)W_in;
        if (tid < KPB) xs[tid] = inputs[k0 + tid];
    }
    if (by == TILES - 1 && tid < 64) out[bx * 64 + tid] = 0.0f;  // zero out head
    __syncthreads();

    const int col4 = bx * 256 + tid;
    const float4* Mp = M + (size_t)k0 * N4 + col4;

    float4 acc = make_float4(0.f, 0.f, 0.f, 0.f);
#pragma unroll 8
    for (int i = 0; i < KPB; ++i) {
        float  s = xs[i];
        float4 m = Mp[(size_t)i * N4];
        acc.x = fmaf(s, m.x, acc.x);
        acc.y = fmaf(s, m.y, acc.y);
        acc.z = fmaf(s, m.z, acc.z);
        acc.w = fmaf(s, m.w, acc.w);
    }
    P4[(size_t)(by * 8 + bx) * 256 + tid] = acc;   // coalesced private store
}

// ---------------------------------------------------------------------------
// K2: blocks [0,64):  out-gemv tile of 128 rows — reduce partials for own rows,
//                     pot_new -> gen -> accumulate into out[0:512] (atomics).
//     blocks [64,128): elementwise — reduce partials, write pot_new to
//                      d_out[512:8704].
// block = 128
// ---------------------------------------------------------------------------
__global__ __launch_bounds__(128)
void finish_kernel(const float* __restrict__ pot,
                   const float* __restrict__ P,     // [136*8][1024] floats
                   const float* __restrict__ W_out,
                   float* __restrict__ out) {
    const int b = blockIdx.x;
    const int t = threadIdx.x;
    if (b < OTILES) {
        // ---- out = tanh(pot_new) @ W_out, 128-row split-K tile ----
        __shared__ float xs[K2_KPB];
        const int k0  = b * K2_KPB;
        const int bx  = k0 >> 10;         // which 1024-col stripe
        const int off = (k0 & 1023) + t;  // offset inside stripe (row k0+t)
        float s = 0.f;
#pragma unroll 8
        for (int by = 0; by < TILES; ++by)
            s += P[(size_t)(by * 8 + bx) * 1024 + off];
        float p  = pot[k0 + t];
        float pn = p + (s - p) * TAU_INV;
        xs[t] = tanhf(pn);
        __syncthreads();

        const float4* Wp = (const float4*)W_out + (size_t)k0 * OUT4 + t;
        float4 acc = make_float4(0.f, 0.f, 0.f, 0.f);
#pragma unroll 8
        for (int i = 0; i < K2_KPB; ++i) {
            float  sx = xs[i];
            float4 m  = Wp[(size_t)i * OUT4];
            acc.x = fmaf(sx, m.x, acc.x);
            acc.y = fmaf(sx, m.y, acc.y);
            acc.z = fmaf(sx, m.z, acc.z);
            acc.w = fmaf(sx, m.w, acc.w);
        }
        float* op = out + (size_t)t * 4;
        atomicAdd(op + 0, acc.x);
        atomicAdd(op + 1, acc.y);
        atomicAdd(op + 2, acc.z);
        atomicAdd(op + 3, acc.w);
    } else {
        // ---- pot_new elementwise -> d_out[512:] ----
        const int j   = (b - OTILES) * 128 + t;
        const int bx  = j >> 10;
        const int off = j & 1023;
        float s = 0.f;
#pragma unroll 8
        for (int by = 0; by < TILES; ++by)
            s += P[(size_t)(by * 8 + bx) * 1024 + off];
        float p  = pot[j];
        float pn = p + (s - p) * TAU_INV;
        out[OUT_SZ + j] = pn;
    }
}

// ---------------------------------------------------------------------------
extern "C" void kernel_launch(void* const* d_in, const int* in_sizes, int n_in,
                              void* d_out, int out_size, void* d_ws, size_t ws_size,
                              hipStream_t stream) {
    const float* inputs   = (const float*)d_in[0];   // [512]
    const float* pot      = (const float*)d_in[1];   // [8192]
    const float* W_in     = (const float*)d_in[2];   // [512, 8192]
    const float* synapses = (const float*)d_in[3];   // [8192, 8192]
    const float* W_out    = (const float*)d_in[4];   // [8192, 512]

    float* out = (float*)d_out;          // [0:512] output, [512:8704] pot_new
    float* P   = (float*)d_ws;           // 136*8*1024 floats = 4.25 MB partials

    // K1: 8 col-stripes x (128 synapse + 8 W_in) k-tiles, no atomics
    accum_kernel<<<dim3(8, TILES), dim3(256), 0, stream>>>(
        pot, inputs, synapses, W_in, (float4*)P, out);

    // K2: 64 out-gemv tiles + 64 elementwise blocks
    finish_kernel<<<dim3(OTILES + N_NEU / 128), dim3(128), 0, stream>>>(
        pot, P, W_out, out);
}